// Round 8
// baseline (661.091 us; speedup 1.0000x reference)
//
#include <hip/hip_runtime.h>
#include <hip/hip_bf16.h>
#include <hip/hip_cooperative_groups.h>
#include <math.h>

namespace cg = cooperative_groups;

#define N_NODES 100000
#define N_EDGES 1600000
#define IN_CH 512
#define HID 64
#define OUT_CH 32
#define MU 0.1f
#define EPS 1e-8f

#define HE (2 * N_EDGES)    // 3.2M endpoints
#define ABLK 625            // build-kernel blocks
#define EPT 20              // endpoints per thread (625*256*20 = 3.2M)
#define NBUCK 391           // bucket = node >> 8 (256 nodes per bucket)

typedef short bf16x8 __attribute__((ext_vector_type(8)));
typedef unsigned short us8 __attribute__((ext_vector_type(8)));
typedef float f32x4 __attribute__((ext_vector_type(4)));

__device__ __forceinline__ short f2bf(float f) {
  __hip_bfloat16 h = __float2bfloat16(f);
  return *reinterpret_cast<short*>(&h);
}
__device__ __forceinline__ float bf2f(unsigned short u) {
  unsigned int b = ((unsigned int)u) << 16;
  return __uint_as_float(b);
}

// ============ fused build: prep + CSR counting sort (cooperative) ============
__global__ __launch_bounds__(256) void k_build(
    const int* __restrict__ ends, const float* __restrict__ W1,
    const float* __restrict__ W2, short* __restrict__ w1t,
    short* __restrict__ w2t, int* __restrict__ bcnt, int* __restrict__ btotal,
    int* __restrict__ bucketbase, int* __restrict__ sbase,
    int* __restrict__ pairs, int* __restrict__ deg, int* __restrict__ rowstart,
    int* __restrict__ adj) {
  cg::grid_group grid = cg::this_grid();
  __shared__ int cnt[NBUCK];
  __shared__ int sh[256];
  __shared__ int ws[4];
  const int t = threadIdx.x;
  const int b = blockIdx.x;

  // phase 0: weight transpose+cast to bf16 (first 136 blocks; independent)
  {
    const int i = b * 256 + t;
    if (i < IN_CH * HID) {
      int k = i / HID, c = i % HID;
      w1t[c * IN_CH + k] = f2bf(W1[i]);
    } else if (i < IN_CH * HID + HID * OUT_CH) {
      int j = i - IN_CH * HID;
      w2t[(j % OUT_CH) * HID + (j / OUT_CH)] = f2bf(W2[j]);
    }
  }

  // phase 1: per-(block,bucket) histogram via LDS atomics
  for (int i = t; i < NBUCK; i += 256) cnt[i] = 0;
  __syncthreads();
  {
    const int base = b * (256 * EPT);
    #pragma unroll
    for (int j = 0; j < EPT; ++j) {
      int u = ends[base + j * 256 + t];
      atomicAdd(&cnt[u >> 8], 1);
    }
  }
  __syncthreads();
  for (int i = t; i < NBUCK; i += 256) bcnt[i * ABLK + b] = cnt[i];

  grid.sync();

  // phase 2: bucket totals (blocks 0..NBUCK-1)
  if (b < NBUCK) {
    int s = 0;
    for (int i = t; i < ABLK; i += 256) s += bcnt[b * ABLK + i];
    #pragma unroll
    for (int k = 1; k < 64; k <<= 1) s += __shfl_xor(s, k);
    if ((t & 63) == 0) ws[t >> 6] = s;
    __syncthreads();
    if (t == 0) btotal[b] = ws[0] + ws[1] + ws[2] + ws[3];
  }

  grid.sync();

  // phase 3: exclusive scan of bucket totals (block 0, 2 chunks of 256)
  if (b == 0) {
    int carry = 0;
    for (int c0 = 0; c0 < NBUCK; c0 += 256) {
      const int idx = c0 + t;
      int v = idx < NBUCK ? btotal[idx] : 0;
      sh[t] = v;
      __syncthreads();
      for (int s = 1; s < 256; s <<= 1) {
        int a = t >= s ? sh[t - s] : 0;
        __syncthreads();
        sh[t] += a;
        __syncthreads();
      }
      if (idx < NBUCK) bucketbase[idx] = carry + sh[t] - v;
      carry += sh[255];
      __syncthreads();
    }
  }

  grid.sync();

  // phase 4: per-bucket scan over block counts -> scatter bases (transposed)
  if (b < NBUCK) {
    int carry = bucketbase[b];
    for (int c0 = 0; c0 < ABLK; c0 += 256) {
      const int idx = c0 + t;
      int v = idx < ABLK ? bcnt[b * ABLK + idx] : 0;
      sh[t] = v;
      __syncthreads();
      for (int s = 1; s < 256; s <<= 1) {
        int a = t >= s ? sh[t - s] : 0;
        __syncthreads();
        sh[t] += a;
        __syncthreads();
      }
      if (idx < ABLK) sbase[idx * NBUCK + b] = carry + sh[t] - v;
      carry += sh[255];
      __syncthreads();
    }
  }

  grid.sync();

  // phase 5: scatter packed (u_local<<24 | nb) into bucket-grouped pairs
  for (int i = t; i < NBUCK; i += 256) cnt[i] = sbase[b * NBUCK + i];
  __syncthreads();
  {
    const int base = b * (256 * EPT);
    #pragma unroll
    for (int j = 0; j < EPT; ++j) {
      const int i = base + j * 256 + t;
      const int u = ends[i];
      const int nb2 = ends[i < N_EDGES ? i + N_EDGES : i - N_EDGES];
      const int slot = atomicAdd(&cnt[u >> 8], 1);
      pairs[slot] = ((u & 255) << 24) | nb2;
    }
  }

  grid.sync();

  // phase 6: per bucket (256 contiguous nodes): deg, rowstart, adj
  if (b < NBUCK) {
    const int pbase = bucketbase[b];
    const int psz = btotal[b];
    cnt[t] = 0;
    __syncthreads();
    for (int i = t; i < psz; i += 256)
      atomicAdd(&cnt[((unsigned)pairs[pbase + i]) >> 24], 1);
    __syncthreads();
    const int d = cnt[t];
    sh[t] = d;
    __syncthreads();
    for (int s = 1; s < 256; s <<= 1) {
      int a = t >= s ? sh[t - s] : 0;
      __syncthreads();
      sh[t] += a;
      __syncthreads();
    }
    const int rs = pbase + sh[t] - d;
    const int v = (b << 8) + t;
    if (v < N_NODES) {
      deg[v] = d;
      rowstart[v] = rs;
    }
    __syncthreads();
    cnt[t] = rs;
    __syncthreads();
    for (int i = t; i < psz; i += 256) {
      const int p = pairs[pbase + i];
      adj[atomicAdd(&cnt[((unsigned)p) >> 24], 1)] = p & 0xFFFFFF;
    }
  }
}

// ---------------- MLP via MFMA; epilogue writes f (fp32) and gs (bf16) --------
__global__ __launch_bounds__(256) void k_mlp(
    const float* __restrict__ x, const short* __restrict__ w1t,
    const float* __restrict__ b1, const short* __restrict__ w2t,
    const float* __restrict__ b2, const int* __restrict__ deg,
    float* __restrict__ f, unsigned short* __restrict__ gs) {
  __shared__ short ht[4][16][72];

  const int t = threadIdx.x;
  const int w = t >> 6;
  const int l = t & 63;
  const int lr = l & 15;
  const int kq = l >> 4;

  const int band = blockIdx.x * 64 + w * 16;
  const int gr = band + lr;
  const int grl = gr < N_NODES ? gr : N_NODES - 1;

  f32x4 acc1[4] = {};
  const float* xrow = x + (size_t)grl * IN_CH + kq * 8;
  #pragma unroll 4
  for (int ksub = 0; ksub < 16; ++ksub) {
    float4 alo = *(const float4*)(xrow + ksub * 32);
    float4 ahi = *(const float4*)(xrow + ksub * 32 + 4);
    bf16x8 a;
    a[0] = f2bf(alo.x); a[1] = f2bf(alo.y); a[2] = f2bf(alo.z); a[3] = f2bf(alo.w);
    a[4] = f2bf(ahi.x); a[5] = f2bf(ahi.y); a[6] = f2bf(ahi.z); a[7] = f2bf(ahi.w);
    #pragma unroll
    for (int ct = 0; ct < 4; ++ct) {
      const int c = ct * 16 + lr;
      bf16x8 bfrag = *(const bf16x8*)&w1t[c * IN_CH + ksub * 32 + kq * 8];
      acc1[ct] = __builtin_amdgcn_mfma_f32_16x16x32_bf16(a, bfrag, acc1[ct], 0, 0, 0);
    }
  }

  #pragma unroll
  for (int ct = 0; ct < 4; ++ct) {
    const int c = ct * 16 + lr;
    const float bb = b1[c];
    #pragma unroll
    for (int r = 0; r < 4; ++r) {
      float h = acc1[ct][r] + bb;
      ht[w][kq * 4 + r][c] = f2bf(h > 0.f ? h : 0.f);
    }
  }
  __syncthreads();

  f32x4 acc2[2] = {};
  #pragma unroll
  for (int ks = 0; ks < 2; ++ks) {
    bf16x8 a2 = *(const bf16x8*)&ht[w][lr][ks * 32 + kq * 8];
    #pragma unroll
    for (int ct = 0; ct < 2; ++ct) {
      const int c = ct * 16 + lr;
      bf16x8 bfrag = *(const bf16x8*)&w2t[c * HID + ks * 32 + kq * 8];
      acc2[ct] = __builtin_amdgcn_mfma_f32_16x16x32_bf16(a2, bfrag, acc2[ct], 0, 0, 0);
    }
  }

  #pragma unroll
  for (int r = 0; r < 4; ++r) {
    const int gr2 = band + kq * 4 + r;
    if (gr2 < N_NODES) {
      const int d = deg[gr2];
      const float di = d > 0 ? 1.0f / (float)d : 0.0f;
      const float disv = sqrtf(di);
      #pragma unroll
      for (int ct = 0; ct < 2; ++ct) {
        const int c = ct * 16 + lr;
        const float fv = acc2[ct][r] + b2[c];
        f[(size_t)gr2 * OUT_CH + c] = fv;
        gs[(size_t)gr2 * OUT_CH + c] = (unsigned short)f2bf(fv * disv);
      }
    }
  }
}

// ---------------- propagation (bf16 gs gather, fp32 accumulate) ----------------
template <bool FINAL>
__global__ __launch_bounds__(256) void k_prop(
    const unsigned short* __restrict__ gs_in, const float* __restrict__ f,
    const int* __restrict__ deg, const int* __restrict__ rowstart,
    const int* __restrict__ adj, float* __restrict__ outf,
    unsigned short* __restrict__ outg) {
  const int v = blockIdx.x * 4 + (threadIdx.x >> 6);
  const int lane = threadIdx.x & 63;
  const int slot = lane >> 2;
  const int cg2 = (lane & 3) << 3;

  const us8 gvu = *(const us8*)&gs_in[v * OUT_CH + cg2];
  float gv[8];
  #pragma unroll
  for (int j = 0; j < 8; ++j) gv[j] = bf2f(gvu[j]);

  const int dg = deg[v];
  const float dinvv = dg > 0 ? 1.0f / (float)dg : 0.0f;
  const float disv = sqrtf(dinvv);
  const int i0 = rowstart[v];

  float accs = 0.f;
  float acca[8] = {0.f, 0.f, 0.f, 0.f, 0.f, 0.f, 0.f, 0.f};

  for (int base = 0; base < dg; base += 16) {
    const int idx = base + slot;
    const bool valid = idx < dg;
    const int u = valid ? adj[i0 + idx] : v;
    const us8 guu = *(const us8*)&gs_in[u * OUT_CH + cg2];
    float gu[8];
    #pragma unroll
    for (int j = 0; j < 8; ++j) gu[j] = bf2f(guu[j]);
    float d, sq;
    d = gv[0] - gu[0]; sq = d * d;
    #pragma unroll
    for (int j = 1; j < 8; ++j) { d = gv[j] - gu[j]; sq = fmaf(d, d, sq); }
    sq += __shfl_xor(sq, 1);
    sq += __shfl_xor(sq, 2);
    const float w = valid ? __frsqrt_rn(sqrtf(sq + EPS)) : 0.f;
    accs += w;
    #pragma unroll
    for (int j = 0; j < 8; ++j) acca[j] = fmaf(w, gu[j], acca[j]);
  }

  #pragma unroll
  for (int s = 4; s <= 32; s <<= 1) {
    accs += __shfl_xor(accs, s);
    #pragma unroll
    for (int j = 0; j < 8; ++j) acca[j] += __shfl_xor(acca[j], s);
  }

  const float alpha = 1.0f / (accs * dinvv + MU);
  const float ad = alpha * disv;
  const float ba = MU * alpha;
  const float4 fv0 = *(const float4*)&f[v * OUT_CH + cg2];
  const float4 fv1 = *(const float4*)&f[v * OUT_CH + cg2 + 4];
  float r[8];
  r[0] = fmaf(ad, acca[0], ba * fv0.x);
  r[1] = fmaf(ad, acca[1], ba * fv0.y);
  r[2] = fmaf(ad, acca[2], ba * fv0.z);
  r[3] = fmaf(ad, acca[3], ba * fv0.w);
  r[4] = fmaf(ad, acca[4], ba * fv1.x);
  r[5] = fmaf(ad, acca[5], ba * fv1.y);
  r[6] = fmaf(ad, acca[6], ba * fv1.z);
  r[7] = fmaf(ad, acca[7], ba * fv1.w);

  if (FINAL) {
    float m = r[0];
    #pragma unroll
    for (int j = 1; j < 8; ++j) m = fmaxf(m, r[j]);
    m = fmaxf(m, __shfl_xor(m, 1));
    m = fmaxf(m, __shfl_xor(m, 2));
    float se = 0.f;
    #pragma unroll
    for (int j = 0; j < 8; ++j) se += __expf(r[j] - m);
    se += __shfl_xor(se, 1);
    se += __shfl_xor(se, 2);
    const float lse = m + __logf(se);
    if (slot == 0) {
      float4 o0 = make_float4(r[0] - lse, r[1] - lse, r[2] - lse, r[3] - lse);
      float4 o1 = make_float4(r[4] - lse, r[5] - lse, r[6] - lse, r[7] - lse);
      *(float4*)&outf[v * OUT_CH + cg2] = o0;
      *(float4*)&outf[v * OUT_CH + cg2 + 4] = o1;
    }
  } else {
    if (slot == 0) {
      us8 o;
      #pragma unroll
      for (int j = 0; j < 8; ++j) o[j] = (unsigned short)f2bf(r[j] * disv);
      *(us8*)&outg[v * OUT_CH + cg2] = o;
    }
  }
}

extern "C" void kernel_launch(void* const* d_in, const int* in_sizes, int n_in,
                              void* d_out, int out_size, void* d_ws, size_t ws_size,
                              hipStream_t stream) {
  const float* x = (const float*)d_in[0];
  const int* ei = (const int*)d_in[1];  // [src(1.6M); dst(1.6M)]
  const float* W1 = (const float*)d_in[2];
  const float* b1 = (const float*)d_in[3];
  const float* W2 = (const float*)d_in[4];
  const float* b2 = (const float*)d_in[5];
  float* out = (float*)d_out;

  float* f = (float*)d_ws;                             // N*32 f32 (12.8MB)
  unsigned short* gsa = (unsigned short*)(f + (size_t)N_NODES * 32);  // N*32 bf16
  unsigned short* gsb = gsa + (size_t)N_NODES * 32;    // N*32 bf16
  int* deg = (int*)(gsb + (size_t)N_NODES * 32);       // N
  int* rowstart = deg + N_NODES;                       // N
  int* adj = rowstart + N_NODES;                       // 2E
  short* w1t = (short*)(adj + 2 * N_EDGES);            // 512*64 bf16
  short* w2t = w1t + IN_CH * HID;                      // 64*32 bf16
  int* bcnt = (int*)(w2t + HID * OUT_CH);              // NBUCK*ABLK
  int* sbase = bcnt + NBUCK * ABLK;                    // ABLK*NBUCK (transposed)
  int* btotal = sbase + NBUCK * ABLK;                  // NBUCK
  int* bucketbase = btotal + NBUCK + 1;                // NBUCK
  int* pairs = (int*)f;                                // overlay (dead until k_mlp)

  void* args[] = {(void*)&ei, (void*)&W1, (void*)&W2, (void*)&w1t, (void*)&w2t,
                  (void*)&bcnt, (void*)&btotal, (void*)&bucketbase, (void*)&sbase,
                  (void*)&pairs, (void*)&deg, (void*)&rowstart, (void*)&adj};
  hipLaunchCooperativeKernel(reinterpret_cast<void*>(k_build), dim3(ABLK),
                             dim3(256), args, 0, stream);
  k_mlp<<<(N_NODES + 63) / 64, 256, 0, stream>>>(x, w1t, b1, w2t, b2, deg, f, gsa);
  k_prop<false><<<N_NODES / 4, 256, 0, stream>>>(gsa, f, deg, rowstart, adj, nullptr, gsb);
  k_prop<true><<<N_NODES / 4, 256, 0, stream>>>(gsb, f, deg, rowstart, adj, out, nullptr);
}

// Round 9
// 282.377 us; speedup vs baseline: 2.3412x; 2.3412x over previous
//
#include <hip/hip_runtime.h>
#include <hip/hip_bf16.h>
#include <math.h>

#define N_NODES 100000
#define N_EDGES 1600000
#define IN_CH 512
#define HID 64
#define OUT_CH 32
#define MU 0.1f
#define EPS 1e-8f

#define HE (2 * N_EDGES)    // 3.2M endpoints
#define ABLK 625            // build blocks
#define EPT 20              // endpoints per thread (625*256*20 = 3.2M)
#define NBUCK 391           // bucket = node >> 8 (256 nodes per bucket)
#define PCAP 10240          // LDS pairs cap per bucket (mean 8192, sigma~91)

typedef short bf16x8 __attribute__((ext_vector_type(8)));
typedef unsigned short us8 __attribute__((ext_vector_type(8)));
typedef float f32x4 __attribute__((ext_vector_type(4)));

__device__ __forceinline__ short f2bf(float f) {
  __hip_bfloat16 h = __float2bfloat16(f);
  return *reinterpret_cast<short*>(&h);
}
__device__ __forceinline__ float bf2f(unsigned short u) {
  unsigned int b = ((unsigned int)u) << 16;
  return __uint_as_float(b);
}

// ---- A: per-(block,bucket) histogram (LDS atomics) + fused weight prep ----
__global__ __launch_bounds__(256) void k_bcount(
    const int* __restrict__ ends, int* __restrict__ bcnt,
    const float* __restrict__ W1, const float* __restrict__ W2,
    short* __restrict__ w1t, short* __restrict__ w2t) {
  const int t = threadIdx.x;
  const int b = blockIdx.x;
  // fused prep (independent; w1t/w2t not read until k_mlp)
  {
    const int i = b * 256 + t;
    if (i < IN_CH * HID) {
      int k = i / HID, c = i % HID;
      w1t[c * IN_CH + k] = f2bf(W1[i]);
    } else if (i < IN_CH * HID + HID * OUT_CH) {
      int j = i - IN_CH * HID;
      w2t[(j % OUT_CH) * HID + (j / OUT_CH)] = f2bf(W2[j]);
    }
  }
  __shared__ int cnt[NBUCK];
  for (int i = t; i < NBUCK; i += 256) cnt[i] = 0;
  __syncthreads();
  const int base = b * (256 * EPT);
  #pragma unroll
  for (int j = 0; j < EPT; ++j) {
    int u = ends[base + j * 256 + t];
    atomicAdd(&cnt[u >> 8], 1);
  }
  __syncthreads();
  for (int i = t; i < NBUCK; i += 256) bcnt[i * ABLK + b] = cnt[i];
}

__global__ __launch_bounds__(256) void k_rowsum(const int* __restrict__ bcnt,
                                                int* __restrict__ btotal) {
  const int b = blockIdx.x;
  int s = 0;
  for (int i = threadIdx.x; i < ABLK; i += 256) s += bcnt[b * ABLK + i];
  #pragma unroll
  for (int k = 1; k < 64; k <<= 1) s += __shfl_xor(s, k);
  __shared__ int ws[4];
  if ((threadIdx.x & 63) == 0) ws[threadIdx.x >> 6] = s;
  __syncthreads();
  if (threadIdx.x == 0) btotal[b] = ws[0] + ws[1] + ws[2] + ws[3];
}

__global__ __launch_bounds__(512) void k_bscan(const int* __restrict__ btotal,
                                               int* __restrict__ bucketbase) {
  __shared__ int sh[512];
  const int t = threadIdx.x;
  int v = t < NBUCK ? btotal[t] : 0;
  sh[t] = v;
  __syncthreads();
  for (int s = 1; s < 512; s <<= 1) {
    int a = t >= s ? sh[t - s] : 0;
    __syncthreads();
    sh[t] += a;
    __syncthreads();
  }
  if (t < NBUCK) bucketbase[t] = sh[t] - v;
}

__global__ __launch_bounds__(256) void k_colscan(const int* __restrict__ bcnt,
                                                 const int* __restrict__ bucketbase,
                                                 int* __restrict__ sbase) {
  __shared__ int sh[256];
  const int b = blockIdx.x;
  const int t = threadIdx.x;
  int carry = bucketbase[b];
  for (int c = 0; c < ABLK; c += 256) {
    const int idx = c + t;
    int v = idx < ABLK ? bcnt[b * ABLK + idx] : 0;
    sh[t] = v;
    __syncthreads();
    for (int s = 1; s < 256; s <<= 1) {
      int a = t >= s ? sh[t - s] : 0;
      __syncthreads();
      sh[t] += a;
      __syncthreads();
    }
    if (idx < ABLK) sbase[idx * NBUCK + b] = carry + sh[t] - v;
    carry += sh[255];
    __syncthreads();
  }
}

// C: scatter packed (u_local<<24 | nb) into bucket-grouped array (LDS cursors)
__global__ __launch_bounds__(256) void k_bscatter(const int* __restrict__ ends,
                                                  const int* __restrict__ sbase,
                                                  int* __restrict__ pairs) {
  __shared__ int cur[NBUCK];
  for (int i = threadIdx.x; i < NBUCK; i += 256)
    cur[i] = sbase[blockIdx.x * NBUCK + i];
  __syncthreads();
  const int base = blockIdx.x * (256 * EPT);
  #pragma unroll
  for (int j = 0; j < EPT; ++j) {
    const int i = base + j * 256 + threadIdx.x;
    const int u = ends[i];
    const int nb = ends[i < N_EDGES ? i + N_EDGES : i - N_EDGES];
    const int slot = atomicAdd(&cur[u >> 8], 1);
    pairs[slot] = ((u & 255) << 24) | nb;
  }
}

// D: per bucket: deg, rowstart, adj — pairs staged in LDS (single global read)
__global__ __launch_bounds__(256) void k_csr(const int* __restrict__ pairs,
                                             const int* __restrict__ bucketbase,
                                             const int* __restrict__ btotal,
                                             int* __restrict__ deg,
                                             int* __restrict__ rowstart,
                                             int* __restrict__ adj) {
  __shared__ int pl[PCAP];
  __shared__ int cnt[256];
  __shared__ int sh[256];
  const int b = blockIdx.x, t = threadIdx.x;
  const int pbase = bucketbase[b];
  const int psz = btotal[b];
  const bool fits = psz <= PCAP;
  cnt[t] = 0;
  __syncthreads();
  if (fits) {
    for (int i = t; i < psz; i += 256) {
      int p = pairs[pbase + i];
      pl[i] = p;
      atomicAdd(&cnt[((unsigned)p) >> 24], 1);
    }
  } else {
    for (int i = t; i < psz; i += 256)
      atomicAdd(&cnt[((unsigned)pairs[pbase + i]) >> 24], 1);
  }
  __syncthreads();
  const int d = cnt[t];
  sh[t] = d;
  __syncthreads();
  for (int s = 1; s < 256; s <<= 1) {
    int a = t >= s ? sh[t - s] : 0;
    __syncthreads();
    sh[t] += a;
    __syncthreads();
  }
  const int rs = pbase + sh[t] - d;
  const int v = (b << 8) + t;
  if (v < N_NODES) {
    deg[v] = d;
    rowstart[v] = rs;
  }
  __syncthreads();
  cnt[t] = rs;
  __syncthreads();
  for (int i = t; i < psz; i += 256) {
    const int p = fits ? pl[i] : pairs[pbase + i];
    adj[atomicAdd(&cnt[((unsigned)p) >> 24], 1)] = p & 0xFFFFFF;
  }
}

// ---------------- MLP via MFMA; epilogue writes f (fp32) and gs (bf16) --------
__global__ __launch_bounds__(256) void k_mlp(
    const float* __restrict__ x, const short* __restrict__ w1t,
    const float* __restrict__ b1, const short* __restrict__ w2t,
    const float* __restrict__ b2, const int* __restrict__ deg,
    float* __restrict__ f, unsigned short* __restrict__ gs) {
  __shared__ short ht[4][16][72];

  const int t = threadIdx.x;
  const int w = t >> 6;
  const int l = t & 63;
  const int lr = l & 15;
  const int kq = l >> 4;

  const int band = blockIdx.x * 64 + w * 16;
  const int gr = band + lr;
  const int grl = gr < N_NODES ? gr : N_NODES - 1;

  f32x4 acc1[4] = {};
  const float* xrow = x + (size_t)grl * IN_CH + kq * 8;
  #pragma unroll 4
  for (int ksub = 0; ksub < 16; ++ksub) {
    float4 alo = *(const float4*)(xrow + ksub * 32);
    float4 ahi = *(const float4*)(xrow + ksub * 32 + 4);
    bf16x8 a;
    a[0] = f2bf(alo.x); a[1] = f2bf(alo.y); a[2] = f2bf(alo.z); a[3] = f2bf(alo.w);
    a[4] = f2bf(ahi.x); a[5] = f2bf(ahi.y); a[6] = f2bf(ahi.z); a[7] = f2bf(ahi.w);
    #pragma unroll
    for (int ct = 0; ct < 4; ++ct) {
      const int c = ct * 16 + lr;
      bf16x8 bfrag = *(const bf16x8*)&w1t[c * IN_CH + ksub * 32 + kq * 8];
      acc1[ct] = __builtin_amdgcn_mfma_f32_16x16x32_bf16(a, bfrag, acc1[ct], 0, 0, 0);
    }
  }

  #pragma unroll
  for (int ct = 0; ct < 4; ++ct) {
    const int c = ct * 16 + lr;
    const float bb = b1[c];
    #pragma unroll
    for (int r = 0; r < 4; ++r) {
      float h = acc1[ct][r] + bb;
      ht[w][kq * 4 + r][c] = f2bf(h > 0.f ? h : 0.f);
    }
  }
  __syncthreads();

  f32x4 acc2[2] = {};
  #pragma unroll
  for (int ks = 0; ks < 2; ++ks) {
    bf16x8 a2 = *(const bf16x8*)&ht[w][lr][ks * 32 + kq * 8];
    #pragma unroll
    for (int ct = 0; ct < 2; ++ct) {
      const int c = ct * 16 + lr;
      bf16x8 bfrag = *(const bf16x8*)&w2t[c * HID + ks * 32 + kq * 8];
      acc2[ct] = __builtin_amdgcn_mfma_f32_16x16x32_bf16(a2, bfrag, acc2[ct], 0, 0, 0);
    }
  }

  #pragma unroll
  for (int r = 0; r < 4; ++r) {
    const int gr2 = band + kq * 4 + r;
    if (gr2 < N_NODES) {
      const int d = deg[gr2];
      const float di = d > 0 ? 1.0f / (float)d : 0.0f;
      const float disv = sqrtf(di);
      #pragma unroll
      for (int ct = 0; ct < 2; ++ct) {
        const int c = ct * 16 + lr;
        const float fv = acc2[ct][r] + b2[c];
        f[(size_t)gr2 * OUT_CH + c] = fv;
        gs[(size_t)gr2 * OUT_CH + c] = (unsigned short)f2bf(fv * disv);
      }
    }
  }
}

// ------- propagation: bf16 gather, 2-deep pipelined neighbor loop -------
template <bool FINAL>
__global__ __launch_bounds__(256) void k_prop(
    const unsigned short* __restrict__ gs_in, const float* __restrict__ f,
    const int* __restrict__ deg, const int* __restrict__ rowstart,
    const int* __restrict__ adj, float* __restrict__ outf,
    unsigned short* __restrict__ outg) {
  const int v = blockIdx.x * 4 + (threadIdx.x >> 6);
  const int lane = threadIdx.x & 63;
  const int slot = lane >> 2;        // 0..15
  const int cg2 = (lane & 3) << 3;   // 0,8,16,24

  const us8 gvu = *(const us8*)&gs_in[v * OUT_CH + cg2];
  float gv[8];
  #pragma unroll
  for (int j = 0; j < 8; ++j) gv[j] = bf2f(gvu[j]);

  const int dg = deg[v];
  const float dinvv = dg > 0 ? 1.0f / (float)dg : 0.0f;
  const float disv = sqrtf(dinvv);
  const int i0 = rowstart[v];

  float accs = 0.f;
  float acca[8] = {0.f, 0.f, 0.f, 0.f, 0.f, 0.f, 0.f, 0.f};

  for (int base = 0; base < dg; base += 32) {
    const int idx0 = base + slot;
    const int idx1 = base + 16 + slot;
    const bool v0 = idx0 < dg;
    const bool v1 = idx1 < dg;
    const int u0 = v0 ? adj[i0 + idx0] : v;
    const int u1 = v1 ? adj[i0 + idx1] : v;
    const us8 gu0u = *(const us8*)&gs_in[u0 * OUT_CH + cg2];
    const us8 gu1u = *(const us8*)&gs_in[u1 * OUT_CH + cg2];
    float gu0[8], gu1[8];
    #pragma unroll
    for (int j = 0; j < 8; ++j) gu0[j] = bf2f(gu0u[j]);
    #pragma unroll
    for (int j = 0; j < 8; ++j) gu1[j] = bf2f(gu1u[j]);
    float d0 = gv[0] - gu0[0];
    float sq0 = d0 * d0;
    float d1 = gv[0] - gu1[0];
    float sq1 = d1 * d1;
    #pragma unroll
    for (int j = 1; j < 8; ++j) {
      d0 = gv[j] - gu0[j]; sq0 = fmaf(d0, d0, sq0);
      d1 = gv[j] - gu1[j]; sq1 = fmaf(d1, d1, sq1);
    }
    sq0 += __shfl_xor(sq0, 1);
    sq1 += __shfl_xor(sq1, 1);
    sq0 += __shfl_xor(sq0, 2);
    sq1 += __shfl_xor(sq1, 2);
    const float w0 = v0 ? __frsqrt_rn(sqrtf(sq0 + EPS)) : 0.f;
    const float w1 = v1 ? __frsqrt_rn(sqrtf(sq1 + EPS)) : 0.f;
    accs += w0 + w1;
    #pragma unroll
    for (int j = 0; j < 8; ++j)
      acca[j] = fmaf(w1, gu1[j], fmaf(w0, gu0[j], acca[j]));
  }

  #pragma unroll
  for (int s = 4; s <= 32; s <<= 1) {
    accs += __shfl_xor(accs, s);
    #pragma unroll
    for (int j = 0; j < 8; ++j) acca[j] += __shfl_xor(acca[j], s);
  }

  const float alpha = 1.0f / (accs * dinvv + MU);
  const float ad = alpha * disv;
  const float ba = MU * alpha;
  const float4 fv0 = *(const float4*)&f[v * OUT_CH + cg2];
  const float4 fv1 = *(const float4*)&f[v * OUT_CH + cg2 + 4];
  float r[8];
  r[0] = fmaf(ad, acca[0], ba * fv0.x);
  r[1] = fmaf(ad, acca[1], ba * fv0.y);
  r[2] = fmaf(ad, acca[2], ba * fv0.z);
  r[3] = fmaf(ad, acca[3], ba * fv0.w);
  r[4] = fmaf(ad, acca[4], ba * fv1.x);
  r[5] = fmaf(ad, acca[5], ba * fv1.y);
  r[6] = fmaf(ad, acca[6], ba * fv1.z);
  r[7] = fmaf(ad, acca[7], ba * fv1.w);

  if (FINAL) {
    float m = r[0];
    #pragma unroll
    for (int j = 1; j < 8; ++j) m = fmaxf(m, r[j]);
    m = fmaxf(m, __shfl_xor(m, 1));
    m = fmaxf(m, __shfl_xor(m, 2));
    float se = 0.f;
    #pragma unroll
    for (int j = 0; j < 8; ++j) se += __expf(r[j] - m);
    se += __shfl_xor(se, 1);
    se += __shfl_xor(se, 2);
    const float lse = m + __logf(se);
    if (slot == 0) {
      float4 o0 = make_float4(r[0] - lse, r[1] - lse, r[2] - lse, r[3] - lse);
      float4 o1 = make_float4(r[4] - lse, r[5] - lse, r[6] - lse, r[7] - lse);
      *(float4*)&outf[v * OUT_CH + cg2] = o0;
      *(float4*)&outf[v * OUT_CH + cg2 + 4] = o1;
    }
  } else {
    if (slot == 0) {
      us8 o;
      #pragma unroll
      for (int j = 0; j < 8; ++j) o[j] = (unsigned short)f2bf(r[j] * disv);
      *(us8*)&outg[v * OUT_CH + cg2] = o;
    }
  }
}

extern "C" void kernel_launch(void* const* d_in, const int* in_sizes, int n_in,
                              void* d_out, int out_size, void* d_ws, size_t ws_size,
                              hipStream_t stream) {
  const float* x = (const float*)d_in[0];
  const int* ei = (const int*)d_in[1];  // [src(1.6M); dst(1.6M)]
  const float* W1 = (const float*)d_in[2];
  const float* b1 = (const float*)d_in[3];
  const float* W2 = (const float*)d_in[4];
  const float* b2 = (const float*)d_in[5];
  float* out = (float*)d_out;

  float* f = (float*)d_ws;                             // N*32 f32 (12.8MB)
  unsigned short* gsa = (unsigned short*)(f + (size_t)N_NODES * 32);  // N*32 bf16
  unsigned short* gsb = gsa + (size_t)N_NODES * 32;    // N*32 bf16
  int* deg = (int*)(gsb + (size_t)N_NODES * 32);       // N
  int* rowstart = deg + N_NODES;                       // N
  int* adj = rowstart + N_NODES;                       // 2E
  short* w1t = (short*)(adj + 2 * N_EDGES);            // 512*64 bf16
  short* w2t = w1t + IN_CH * HID;                      // 64*32 bf16
  int* bcnt = (int*)(w2t + HID * OUT_CH);              // NBUCK*ABLK
  int* sbase = bcnt + NBUCK * ABLK;                    // ABLK*NBUCK (transposed)
  int* btotal = sbase + NBUCK * ABLK;                  // NBUCK
  int* bucketbase = btotal + NBUCK + 1;                // NBUCK
  int* pairs = (int*)f;                                // overlay (dead until k_mlp)

  k_bcount<<<ABLK, 256, 0, stream>>>(ei, bcnt, W1, W2, w1t, w2t);
  k_rowsum<<<NBUCK, 256, 0, stream>>>(bcnt, btotal);
  k_bscan<<<1, 512, 0, stream>>>(btotal, bucketbase);
  k_colscan<<<NBUCK, 256, 0, stream>>>(bcnt, bucketbase, sbase);
  k_bscatter<<<ABLK, 256, 0, stream>>>(ei, sbase, pairs);
  k_csr<<<NBUCK, 256, 0, stream>>>(pairs, bucketbase, btotal, deg, rowstart, adj);
  k_mlp<<<(N_NODES + 63) / 64, 256, 0, stream>>>(x, w1t, b1, w2t, b2, deg, f, gsa);
  k_prop<false><<<N_NODES / 4, 256, 0, stream>>>(gsa, f, deg, rowstart, adj, nullptr, gsb);
  k_prop<true><<<N_NODES / 4, 256, 0, stream>>>(gsb, f, deg, rowstart, adj, out, nullptr);
}